// Round 4
// baseline (1179.175 us; speedup 1.0000x reference)
//
#include <hip/hip_runtime.h>

// RecyclingEmbedder: out[i][j][p] = b[p] + (bin(d_ij) fired ? W[p][bin] : 0)
// d_ij = |x_i - x_j|^2, bins = linspace(3.25,20.75,15)^2, strict >lower & <upper.
// Output = 16-row table lookup -> pure write-BW problem (1.208 GB fp32).
//
// R3 lesson: reported dur_us includes a ~775us harness poison fill; kernel was
// ~400us, latency-bound on the per-store ds_read_u8 -> ds_read_b128 chain.
// This version: per-wave contiguous j-range, wave-uniform 16-idx prefetch
// (one ds_read_b128 per 8 stores, pipelined one macro ahead), 8 independent
// table-read+store pairs per macro.

#define NBINS 15
#define NPTS  1536
#define DPAIR 128
#define ROW_F4 (NPTS * DPAIR / 4)   // 49152 float4 per output row i

typedef float f32x4 __attribute__((ext_vector_type(4)));
typedef unsigned u32x4 __attribute__((ext_vector_type(4)));

__global__ __launch_bounds__(256) void recycling_embedder_kernel(
    const float* __restrict__ x,   // [NPTS,3]
    const float* __restrict__ W,   // [DPAIR,NBINS] row-major
    const float* __restrict__ b,   // [DPAIR]
    float* __restrict__ out) {     // [NPTS,NPTS,DPAIR]
    __shared__ float table[16 * DPAIR];                                   // 8 KB
    __shared__ unsigned char idx_lds[NPTS] __attribute__((aligned(16)));  // 1.5 KB

    const int i = blockIdx.x;
    const int t = threadIdx.x;

    // squared bin edges: edges are exact multiples of 0.25 -> exact fp32;
    // squaring rounds identically to numpy's **2 in float32.
    float bins[NBINS];
#pragma unroll
    for (int k = 0; k < NBINS; ++k) {
        float e = 3.25f + 1.25f * (float)k;
        bins[k] = e * e;
    }

    // Row table: row 0 = b (no bin fired), row k = b + W[:,k-1].
    for (int e = t; e < 16 * DPAIR; e += 256) {
        int row = e >> 7;
        int p   = e & (DPAIR - 1);
        float v = b[p];
        if (row > 0) v += W[p * NBINS + (row - 1)];
        table[e] = v;
    }

    // Bin index for every j at this block's fixed i.
    const float xi0 = x[i * 3 + 0];
    const float xi1 = x[i * 3 + 1];
    const float xi2 = x[i * 3 + 2];
    for (int j = t; j < NPTS; j += 256) {
        float d;
        {
            // Bit-exact vs numpy: individually-rounded squares, left-to-right
            // sum, no fma contraction.
#pragma clang fp contract(off)
            float dx = xi0 - x[j * 3 + 0];
            float dy = xi1 - x[j * 3 + 1];
            float dz = xi2 - x[j * 3 + 2];
            d = dx * dx + dy * dy + dz * dz;
        }
        int cnt = 0, eq = 0;
#pragma unroll
        for (int k = 0; k < NBINS; ++k) {
            cnt += (d > bins[k]) ? 1 : 0;
            eq  |= (d == bins[k]) ? 1 : 0;
        }
        idx_lds[j] = (unsigned char)(eq ? 0 : cnt);  // edge hit -> row 0 (b only)
    }
    __syncthreads();

    // ---- Streaming phase ----
    // Wave w owns j in [384w, 384w+384). Per macro-iter: 16 j's; one uniform
    // ds_read_b128 fetches their idx bytes (broadcast); 8 inner iters store
    // 2 j-rows each (wave64 x float4 = 1 KiB coalesced).
    const f32x4* table4 = (const f32x4*)table;
    const u32x4* idxv = (const u32x4*)idx_lds;
    f32x4* orow = (f32x4*)out + (size_t)i * ROW_F4;

    const int w      = t >> 6;          // wave 0..3
    const int lane   = t & 63;
    const int h      = lane >> 5;       // 0/1: which j of the pair
    const int within = lane & 31;       // float4 within 128-float feature row
    const unsigned hsh = (unsigned)h * 8;  // byte shift for idx extraction

    u32x4 r = idxv[w * 24];             // prefetch macro 0
#pragma unroll 1
    for (int m = 0; m < 24; ++m) {
        u32x4 rn = idxv[w * 24 + (m < 23 ? m + 1 : 23)];  // prefetch next
        const int jb = w * 384 + m * 16;
        f32x4* dst = orow + (size_t)(jb + h) * 32 + within;
        unsigned rr[4] = {r.x, r.y, r.z, r.w};
#pragma unroll
        for (int k = 0; k < 8; ++k) {
            // idx byte position within the 16-byte group = 2k + h
            unsigned dw    = rr[k >> 1];
            unsigned shift = (unsigned)(((2 * k) & 3) * 8) + hsh;
            unsigned idx   = (dw >> shift) & 0xFFu;
            f32x4 v = table4[idx * 32 + within];
            dst[(size_t)(2 * k) * 32] = v;
        }
        r = rn;
    }
}

extern "C" void kernel_launch(void* const* d_in, const int* in_sizes, int n_in,
                              void* d_out, int out_size, void* d_ws, size_t ws_size,
                              hipStream_t stream) {
    const float* x = (const float*)d_in[0];
    const float* W = (const float*)d_in[1];
    const float* b = (const float*)d_in[2];
    float* out = (float*)d_out;

    // One block per output row i: 1536 blocks, 4 waves each.
    dim3 grid(NPTS), block(256);
    recycling_embedder_kernel<<<grid, block, 0, stream>>>(x, W, b, out);
}